// Round 1
// 63.520 us; speedup vs baseline: 1.0035x; 1.0035x over previous
//
#include <hip/hip_runtime.h>
#include <math.h>

#define BATCH 256
#define NF 512
#define NQ 16
#define NC 10

// Closed-form collapse of the product-state quantum circuit (no entangling
// gates -> product state):
//   exp_vals[b,q] = cos(encoded[b,15-q]) * cos(sum_d theta[d*16 + (15-q)])
//   logits = exp_vals @ cls_w^T + cls_b
//
// Latency-stripped version:
//  - no LDS staging of x (16-lane groups read the 2KB row via L1; removes
//    one __syncthreads + LDS round trip from the critical path)
//  - float4 global loads: 8+8 dwordx4 per lane instead of 32+32 scalars
//  - classifier weights / bias / theta / enc_b prefetched at kernel entry so
//    their cold HBM miss (caches are poison-thrashed each iteration) overlaps
//    the dot phase instead of serializing after the barrier.
// 1 block per batch row, 256 threads = 4 waves; 16 lanes per qubit.
__global__ __launch_bounds__(256) void hybrid_fcl_kernel(
    const float* __restrict__ x,      // (256,512)
    const float* __restrict__ enc_w,  // (16,512)
    const float* __restrict__ enc_b,  // (16,)
    const float* __restrict__ theta,  // (64,)
    const float* __restrict__ cls_w,  // (10,16)
    const float* __restrict__ cls_b,  // (10,)
    float* __restrict__ out)          // (256,10)
{
    __shared__ float s_ev[NQ];

    const int b = blockIdx.x;
    const int t = threadIdx.x;

    const int wave = t >> 6;       // 0..3
    const int lane = t & 63;
    const int g    = lane >> 4;    // qubit sub-group within wave: 0..3
    const int s    = lane & 15;    // lane within sub-group
    const int p    = wave * 4 + g; // qubit kron-position 0..15

    // ---- early issue: classifier row prefetch (consumed after the barrier) ----
    float cb = 0.f;
    float4 cw0, cw1, cw2, cw3;
    if (t < NC) {
        const float4* cwr = reinterpret_cast<const float4*>(cls_w + t * NQ);
        cb  = cls_b[t];
        cw0 = cwr[0]; cw1 = cwr[1]; cw2 = cwr[2]; cw3 = cwr[3];
    }

    // ---- early issue: per-qubit scalars (consumed after the dot) ----
    const float th = theta[p] + theta[p + 16] + theta[p + 32] + theta[p + 48];
    const float eb = enc_b[p];

    // ---- 512-dot via float4: lane s covers float4 indices s + 16j, j=0..7 ----
    const float4* __restrict__ x4 = reinterpret_cast<const float4*>(x + b * NF);
    const float4* __restrict__ w4 = reinterpret_cast<const float4*>(enc_w + p * NF);

    float ax = 0.f, ay = 0.f, az = 0.f, aw = 0.f;
    #pragma unroll
    for (int j = 0; j < 8; ++j) {
        const float4 xv = x4[s + 16 * j];
        const float4 wv = w4[s + 16 * j];
        ax = fmaf(xv.x, wv.x, ax);
        ay = fmaf(xv.y, wv.y, ay);
        az = fmaf(xv.z, wv.z, az);
        aw = fmaf(xv.w, wv.w, aw);
    }
    float acc = (ax + ay) + (az + aw);

    // reduce across the 16 lanes of this sub-group
    acc += __shfl_down(acc, 8, 16);
    acc += __shfl_down(acc, 4, 16);
    acc += __shfl_down(acc, 2, 16);
    acc += __shfl_down(acc, 1, 16);

    if (s == 0) {
        // bit-index q = 15 - kron-position p
        s_ev[NQ - 1 - p] = __cosf(acc + eb) * __cosf(th);
    }
    __syncthreads();

    // classifier: 10 outputs, 16-dot each (weights already in registers)
    if (t < NC) {
        float r = cb;
        r = fmaf(s_ev[0],  cw0.x, r);
        r = fmaf(s_ev[1],  cw0.y, r);
        r = fmaf(s_ev[2],  cw0.z, r);
        r = fmaf(s_ev[3],  cw0.w, r);
        r = fmaf(s_ev[4],  cw1.x, r);
        r = fmaf(s_ev[5],  cw1.y, r);
        r = fmaf(s_ev[6],  cw1.z, r);
        r = fmaf(s_ev[7],  cw1.w, r);
        r = fmaf(s_ev[8],  cw2.x, r);
        r = fmaf(s_ev[9],  cw2.y, r);
        r = fmaf(s_ev[10], cw2.z, r);
        r = fmaf(s_ev[11], cw2.w, r);
        r = fmaf(s_ev[12], cw3.x, r);
        r = fmaf(s_ev[13], cw3.y, r);
        r = fmaf(s_ev[14], cw3.z, r);
        r = fmaf(s_ev[15], cw3.w, r);
        out[b * NC + t] = r;
    }
}

extern "C" void kernel_launch(void* const* d_in, const int* in_sizes, int n_in,
                              void* d_out, int out_size, void* d_ws, size_t ws_size,
                              hipStream_t stream) {
    const float* x     = (const float*)d_in[0];
    const float* enc_w = (const float*)d_in[1];
    const float* enc_b = (const float*)d_in[2];
    const float* theta = (const float*)d_in[3];
    const float* cls_w = (const float*)d_in[4];
    const float* cls_b = (const float*)d_in[5];
    float* out = (float*)d_out;

    hybrid_fcl_kernel<<<BATCH, 256, 0, stream>>>(x, enc_w, enc_b, theta, cls_w, cls_b, out);
}